// Round 3
// baseline (395.105 us; speedup 1.0000x reference)
//
#include <hip/hip_runtime.h>

// B=4, T=4096, D=1024. Inputs/outputs fp32. GEMM in bf16 MFMA.
// Pipeline: ln_conv -> gemm1 (+fused per-chunk scan aggregates) -> combine -> final -> gemm2.
// Numerics: la = log(alpha+1e-8) <= ~1e-8, so global max of cumsum ~= la[t=0] (error <= 4e-5);
// m is read from la row t=0 in combine; no max machinery anywhere.
// R3: gemm256_core rebuilt as the measured m201-style 8-phase schedule: per phase
//     {ds_read burst} s_barrier, lgkmcnt(0), {16 independent MFMA (ks-outer)}, s_barrier;
//     stage(t+2) + counted vmcnt(8) at phases 4/8 only (publish barrier follows vmcnt --
//     per-wave vmcnt + s_barrier = cross-wave landed guarantee). T2 16B-slot XOR swizzle
//     (bank conflicts measured 0) and bijective XCD chunking kept from R2.
#define D_DIM 1024
#define B_DIM 4
#define T_DIM 4096
#define M_DIM (B_DIM * T_DIM)   // 16384 rows
#define CHUNK 32
#define NCHUNK (T_DIM / CHUNK)  // 128
#define NWAVE_C 16              // waves per combine block
#define SEG (NCHUNK / NWAVE_C)  // 8 chunks per wave in combine
#define NKT (D_DIM / 64)        // 16 K-tiles of 64

typedef unsigned short u16;
typedef __attribute__((ext_vector_type(8))) __bf16 bf16x8;
typedef __attribute__((ext_vector_type(4))) float f32x4;

__device__ __forceinline__ float bf2f(u16 u) {
    union { unsigned int i; float f; } v;
    v.i = ((unsigned int)u) << 16;
    return v.f;
}
__device__ __forceinline__ u16 f2bf(float f) {
    union { float f; unsigned int i; } v;
    v.f = f;
    unsigned int u = v.i;
    unsigned int r = (u + 0x7fffu + ((u >> 16) & 1u)) >> 16;
    return (u16)r;
}
__device__ __forceinline__ float fast_tanh(float v) {
    float e = __expf(2.f * v);
    return 1.f - 2.f / (e + 1.f);
}

#define GLOAD16(g, l)                                                   \
    __builtin_amdgcn_global_load_lds(                                   \
        (const __attribute__((address_space(1))) void*)(g),             \
        (__attribute__((address_space(3))) void*)(l), 16, 0, 0)

#define BAR()                                      \
    do {                                           \
        __builtin_amdgcn_sched_barrier(0);         \
        asm volatile("" ::: "memory");             \
        __builtin_amdgcn_s_barrier();              \
        asm volatile("" ::: "memory");             \
        __builtin_amdgcn_sched_barrier(0);         \
    } while (0)

#define WAITVM(N) asm volatile("s_waitcnt vmcnt(" #N ")" ::: "memory")
#define LGKM0()                                    \
    do {                                           \
        asm volatile("s_waitcnt lgkmcnt(0)" ::: "memory"); \
        __builtin_amdgcn_sched_barrier(0);         \
    } while (0)

// ---------------- fused weight-convert (blocks 0..2047) + wave-per-row LayerNorm ----------
__global__ __launch_bounds__(256) void ln_conv_kernel(const float* __restrict__ x,
                                                      const float* __restrict__ w,
                                                      const float* __restrict__ b,
                                                      u16* __restrict__ xn,
                                                      const float* __restrict__ Wf,
                                                      const float* __restrict__ Wr,
                                                      u16* __restrict__ da,
                                                      u16* __restrict__ db) {
    int tid = threadIdx.x;
    if (blockIdx.x < 2048) {            // convert: 2 x 262144 float4s
        int i = blockIdx.x * 256 + tid;
        const float* s = (i < 262144) ? Wf : Wr;
        u16* dp = (i < 262144) ? da : db;
        int j = i & 262143;
        float4 v = ((const float4*)s)[j];
        ushort4 o;
        o.x = f2bf(v.x); o.y = f2bf(v.y); o.z = f2bf(v.z); o.w = f2bf(v.w);
        ((ushort4*)dp)[j] = o;
        return;
    }
    // LN: one wave per row, 4 rows per block, no __syncthreads
    int wv = tid >> 6, lane = tid & 63;
    int row = (blockIdx.x - 2048) * 4 + wv;
    const float4* xr = (const float4*)(x + (size_t)row * D_DIM);
    float4 xv[4];
    #pragma unroll
    for (int k = 0; k < 4; k++) xv[k] = xr[lane + 64 * k];
    float s = 0.f, s2 = 0.f;
    #pragma unroll
    for (int k = 0; k < 4; k++) {
        s  += xv[k].x + xv[k].y + xv[k].z + xv[k].w;
        s2 += xv[k].x * xv[k].x + xv[k].y * xv[k].y
            + xv[k].z * xv[k].z + xv[k].w * xv[k].w;
    }
    #pragma unroll
    for (int o = 1; o < 64; o <<= 1) {
        s  += __shfl_xor(s, o, 64);
        s2 += __shfl_xor(s2, o, 64);
    }
    float mu = s * (1.0f / D_DIM);
    float var = s2 * (1.0f / D_DIM) - mu * mu;
    float rs = rsqrtf(var + 1e-5f);
    ushort4* xo = (ushort4*)(xn + (size_t)row * D_DIM);
    #pragma unroll
    for (int k = 0; k < 4; k++) {
        float4 wv4 = ((const float4*)w)[lane + 64 * k];
        float4 bv4 = ((const float4*)b)[lane + 64 * k];
        ushort4 o;
        o.x = f2bf((xv[k].x - mu) * rs * wv4.x + bv4.x);
        o.y = f2bf((xv[k].y - mu) * rs * wv4.y + bv4.y);
        o.z = f2bf((xv[k].z - mu) * rs * wv4.z + bv4.z);
        o.w = f2bf((xv[k].w - mu) * rs * wv4.w + bv4.w);
        xo[lane + 64 * k] = o;
    }
}

// ---------------- 256x256 BK=64 8-phase counted-vmcnt GEMM core (fills acc[8][4]) --------
// A [M][1024], B [N][1024] row-major bf16 (C = A.B^T slice). 512 thr = 8 waves (2m x 4n).
// LDS: [2 dbuf][256 rows][64 cols] per operand, 16B-slot XOR swizzle slot^=(row&7),
// staged via pre-swizzled GLOBAL source (linear gload_lds dest), un-swizzled on ds_read.
// Iteration = 2 K-tiles (ta->buf0, tb->buf1), 8 phases. Per phase:
//   [ds_read burst] BAR LGKM0 [setprio(1) 16 MFMA setprio(0)] BAR
// Stage(t+2)+vmcnt(8) at Ph4, stage(t+3)+vmcnt(8) at Ph8; the BAR after each vmcnt
// publishes the landed buffer cross-wave before any ds_read of it. Stage-issue to a
// buffer only after the all-waves barrier of its last read phase (Ph3-end / Ph7-end).
__device__ __forceinline__ void gemm256_core(const u16* __restrict__ AG,
                                             const u16* __restrict__ BG,
                                             int tile_m, int tile_n,
                                             u16* ldsA, u16* ldsB,
                                             f32x4 (*acc)[4]) {
    int tid  = threadIdx.x;
    int wave = tid >> 6, lane = tid & 63;
    int wr = wave >> 2, wc = wave & 3;
    int q = lane >> 4;
    // staging: thread covers LDS bytes j*8192 + tid*16 (j=0..3) => local row j*64+(tid>>3),
    // 16B slot tid&7. Source col-slot pre-swizzled: (tid&7) ^ (row&7).
    int srow = tid >> 3;
    int scol = ((tid & 7) ^ (srow & 7)) * 8;
    const u16* gA = AG + (size_t)(tile_m + srow) * D_DIM + scol;
    const u16* gB = BG + (size_t)(tile_n + srow) * D_DIM + scol;
    int ldst = wave * 512;   // u16 offset: wave-uniform gload dest base within 8KB pass
    // fragment read: local row m, u16 off = m*64 + ((ks*4+q)^(m&7))*8 ; m&7 == lane&7
    int aRow = wr * 128 + (lane & 15);
    int bRow = wc * 64 + (lane & 15);
    int x7 = lane & 7;
    int s0 = (q ^ x7) * 8;          // ks=0 slot
    int s1 = ((4 | q) ^ x7) * 8;    // ks=1 slot

#define STG4(ldsbase, gsrc, koff)                                        \
    do {                                                                 \
        _Pragma("unroll") for (int j = 0; j < 4; j++)                    \
            GLOAD16((gsrc) + (size_t)j * (64 * D_DIM) + (koff),          \
                    (ldsbase) + j * 4096 + ldst);                        \
    } while (0)

#define RD_A(dst, base, mo)                                              \
    do {                                                                 \
        _Pragma("unroll") for (int mi_ = 0; mi_ < 4; mi_++) {            \
            dst[mi_][0] = *(const bf16x8*)((base) + ((mo) + mi_) * 1024 + s0); \
            dst[mi_][1] = *(const bf16x8*)((base) + ((mo) + mi_) * 1024 + s1); \
        }                                                                \
    } while (0)

#define RD_B(dst, base, no)                                              \
    do {                                                                 \
        _Pragma("unroll") for (int ni_ = 0; ni_ < 2; ni_++) {            \
            dst[ni_][0] = *(const bf16x8*)((base) + ((no) + ni_) * 1024 + s0); \
            dst[ni_][1] = *(const bf16x8*)((base) + ((no) + ni_) * 1024 + s1); \
        }                                                                \
    } while (0)

// 16 MFMA, ks-outer: adjacent instructions always target different acc (dep distance 8).
// Per-acc order still ks0 then ks1 -> bit-identical accumulation.
#define MMQ(Af, Bf, mo, no)                                              \
    do {                                                                 \
        __builtin_amdgcn_s_setprio(1);                                   \
        _Pragma("unroll") for (int ks_ = 0; ks_ < 2; ks_++)              \
            _Pragma("unroll") for (int mi_ = 0; mi_ < 4; mi_++)          \
                _Pragma("unroll") for (int ni_ = 0; ni_ < 2; ni_++)      \
                    acc[(mo) + mi_][(no) + ni_] =                        \
                        __builtin_amdgcn_mfma_f32_16x16x32_bf16(         \
                            Af[mi_][ks_], Bf[ni_][ks_],                  \
                            acc[(mo) + mi_][(no) + ni_], 0, 0, 0);       \
        __builtin_amdgcn_s_setprio(0);                                   \
    } while (0)

    const u16* pA0 = ldsA + aRow * 64;
    const u16* pA1 = ldsA + 16384 + aRow * 64;
    const u16* pB0 = ldsB + bRow * 64;
    const u16* pB1 = ldsB + 16384 + bRow * 64;
    bf16x8 A0[4][2], A1[4][2], B0[2][2], B1[2][2];

    // prologue: stage t0 (buf0, 8 loads) + t1 (buf1, 8); land t0, keep t1 in flight; publish.
    STG4(ldsA, gA, 0);
    STG4(ldsB, gB, 0);
    STG4(ldsA + 16384, gA, 64);
    STG4(ldsB + 16384, gB, 64);
    WAITVM(8);
    BAR();

    for (int i = 0; i < NKT / 2; i++) {
        // ---------------- tile ta = 2i (buf0) ----------------
        // Ph1
        RD_A(A0, pA0, 0);
        RD_B(B0, pB0, 0);
        BAR(); LGKM0();
        MMQ(A0, B0, 0, 0);
        BAR();
        // Ph2
        RD_B(B1, pB0, 2);
        BAR(); LGKM0();
        MMQ(A0, B1, 0, 2);
        BAR();
        // Ph3 (last read of buf0 this iteration)
        RD_A(A1, pA0, 4);
        BAR(); LGKM0();
        MMQ(A1, B1, 4, 2);
        BAR();
        // Ph4: stage t+2 -> buf0 (safe: all buf0 reads done at Ph3-end barrier);
        // vmcnt(8) lands tile tb (buf1); BAR publishes it cross-wave.
        if (i + 1 < NKT / 2) {
            STG4(ldsA, gA, (size_t)(2 * i + 2) * 64);
            STG4(ldsB, gB, (size_t)(2 * i + 2) * 64);
            WAITVM(8);
        } else {
            WAITVM(0);
        }
        BAR();
        MMQ(A1, B0, 4, 0);   // regs only
        BAR();
        // ---------------- tile tb = 2i+1 (buf1) ----------------
        // Ph5
        RD_A(A0, pA1, 0);
        RD_B(B0, pB1, 0);
        BAR(); LGKM0();
        MMQ(A0, B0, 0, 0);
        BAR();
        // Ph6
        RD_B(B1, pB1, 2);
        BAR(); LGKM0();
        MMQ(A0, B1, 0, 2);
        BAR();
        // Ph7 (last read of buf1 this iteration)
        RD_A(A1, pA1, 4);
        BAR(); LGKM0();
        MMQ(A1, B1, 4, 2);
        BAR();
        // Ph8: stage t+3 -> buf1 (safe after Ph7-end barrier); vmcnt(8) lands t+2; publish.
        if (i + 1 < NKT / 2) {
            STG4(ldsA + 16384, gA, (size_t)(2 * i + 3) * 64);
            STG4(ldsB + 16384, gB, (size_t)(2 * i + 3) * 64);
            WAITVM(8);
        } else {
            WAITVM(0);
        }
        BAR();
        MMQ(A1, B0, 4, 0);   // regs only
        BAR();
    }
#undef STG4
#undef RD_A
#undef RD_B
#undef MMQ
}

// ---------------- GEMM1: alpha=sigmoid(xn@Wf^T+bf+ab); writes la (bf16) and, fused,
// per-chunk scan aggregates S = sum(la over 32 t), Tb = sum(bx*exp(local inclusive cumsum)).
// Wave owns 128x64 = 4 chunks (mi pairs); prefix over q=lane>>4 via shfl_up as before.
__global__ __launch_bounds__(512, 2) void gemm1_kernel(const u16* __restrict__ xn,
                                                       const u16* __restrict__ Wfc,
                                                       const float* __restrict__ bf_,
                                                       const float* __restrict__ ab,
                                                       const float* __restrict__ bs,
                                                       u16* __restrict__ out_la,
                                                       float* __restrict__ Sg,
                                                       float* __restrict__ Tg) {
    __shared__ __align__(16) u16 ldsA[2][16384];
    __shared__ __align__(16) u16 ldsB[2][16384];
    // bijective XCD chunking: 256 blocks = 8 XCD x (8 m-panels x 4 n-tiles)
    int flat = blockIdx.y * 4 + blockIdx.x;
    int xcd = flat & 7, p = flat >> 3;
    int tile_m = (xcd * 8 + (p >> 2)) * 256;
    int tile_n = (p & 3) * 256;
    f32x4 acc[8][4] = {};
    gemm256_core(xn, Wfc, tile_m, tile_n, &ldsA[0][0], &ldsB[0][0], acc);

    // epilogue: C/D layout col=lane&15 (+ni*16), row=(lane>>4)*4+r (+mi*16) [m89-verified]
    int tid = threadIdx.x, wave = tid >> 6, lane = tid & 63;
    int wr = wave >> 2, wc = wave & 3;
    float abv = ab[0], bsv = bs[0];
    int q = lane >> 4, l = lane & 15;
    #pragma unroll
    for (int ni = 0; ni < 4; ni++) {
        int col = tile_n + wc * 64 + ni * 16 + l;
        float bcol = bf_[col];
        #pragma unroll
        for (int ch = 0; ch < 4; ch++) {   // chunk (32 rows) = mi pair {2ch, 2ch+1}
            float lav[2][4], bxv[2][4];
            #pragma unroll
            for (int h = 0; h < 2; h++) {
                int mi = 2 * ch + h;
                #pragma unroll
                for (int r = 0; r < 4; r++) {
                    int row = tile_m + wr * 128 + mi * 16 + q * 4 + r;
                    float z = acc[mi][ni][r] + bcol + abv;
                    float alpha = 1.f / (1.f + __expf(-z));
                    float la_ = __logf(alpha + 1e-8f);
                    float xv = bf2f(xn[(size_t)row * D_DIM + col]);
                    lav[h][r] = la_;
                    bxv[h][r] = bsv * (1.f - alpha) * xv;
                    out_la[(size_t)row * D_DIM + col] = f2bf(la_);
                }
            }
            // wave-local chunk scan: t = h*16 + q*4 + r
            float s0 = lav[0][0] + lav[0][1] + lav[0][2] + lav[0][3];
            float s1 = lav[1][0] + lav[1][1] + lav[1][2] + lav[1][3];
            float x0 = s0, x1 = s1, y;
            y = __shfl_up(x0, 16, 64); if (q >= 1) x0 += y;
            y = __shfl_up(x0, 32, 64); if (q >= 2) x0 += y;
            y = __shfl_up(x1, 16, 64); if (q >= 1) x1 += y;
            y = __shfl_up(x1, 32, 64); if (q >= 2) x1 += y;
            float t0 = __shfl(x0, l + 48, 64);   // totals from q=3 lane
            float t1 = __shfl(x1, l + 48, 64);
            float e0 = x0 - s0, e1 = x1 - s1;    // exclusive prefixes over q
            float pr = e0, Tp = 0.f;
            #pragma unroll
            for (int r = 0; r < 4; r++) { pr += lav[0][r]; Tp += bxv[0][r] * __expf(pr); }
            pr = t0 + e1;
            #pragma unroll
            for (int r = 0; r < 4; r++) { pr += lav[1][r]; Tp += bxv[1][r] * __expf(pr); }
            Tp += __shfl_xor(Tp, 16, 64);
            Tp += __shfl_xor(Tp, 32, 64);
            if (q == 0) {
                int cidx = ((tile_m + wr * 128) >> 5) + ch;   // = b*NCHUNK + chunk
                Sg[(size_t)cidx * D_DIM + col] = t0 + t1;
                Tg[(size_t)cidx * D_DIM + col] = Tp;
            }
        }
    }
}

// ---------------- combine: per (b,d), prefix over 128 chunks. m = la[b, t=0, d]. ----------
__global__ __launch_bounds__(1024) void scan_combine(const u16* __restrict__ la,
                                                     const float* __restrict__ S,
                                                     const float* __restrict__ Tb,
                                                     float* __restrict__ Of,
                                                     float* __restrict__ SSp) {
    __shared__ float lsS[NWAVE_C][64], lsW[NWAVE_C][64];
    int b = blockIdx.x >> 4;
    int dg = blockIdx.x & 15;
    int wave = threadIdx.x >> 6, lane = threadIdx.x & 63;
    int d = dg * 64 + lane;
    float m = bf2f(la[(size_t)(b * T_DIM) * D_DIM + d]);   // cumsum[0] ~= global max
    size_t base = ((size_t)b * NCHUNK) * D_DIM + d;
    int c0 = wave * SEG;

    float OfR[SEG], wR[SEG];
    float Or = 0.f, w = 0.f;
    #pragma unroll
    for (int j = 0; j < SEG; j++) {
        size_t ci = base + (size_t)(c0 + j) * D_DIM;
        OfR[j] = Or;
        wR[j]  = w;
        w  += __expf(Or) * Tb[ci];
        Or += S[ci];
    }
    lsS[wave][lane] = Or; lsW[wave][lane] = w;
    __syncthreads();

    float o = 0.f, s = 0.f, myO = 0.f, myS = 0.f;
    #pragma unroll
    for (int w2 = 0; w2 < NWAVE_C; w2++) {
        if (w2 == wave) { myO = o; myS = s; }
        s += __expf(o - m) * lsW[w2][lane];
        o += lsS[w2][lane];
    }

    float em = __expf(myO - m);
    #pragma unroll
    for (int j = 0; j < SEG; j++) {
        size_t ci = base + (size_t)(c0 + j) * D_DIM;
        Of[ci]  = myO + OfR[j] - m;
        SSp[ci] = myS + em * wR[j];
    }
}

// ---------------- final: scale=exp(Of+p), s_star=SSp+cumsum, out=s_star/(scale+1e-8) -----
// 4 cols/thread; osc aliases xn (reads at idx precede the write at idx, same thread).
__global__ __launch_bounds__(256) void scan_final(const u16* __restrict__ la,
                                                  const u16* __restrict__ xn,
                                                  const float* __restrict__ bs,
                                                  const float* __restrict__ Of,
                                                  const float* __restrict__ SSp,
                                                  u16* __restrict__ osc) {
    int bc = blockIdx.x;
    int b = bc >> 7, c = bc & (NCHUNK - 1);
    int col0 = threadIdx.x * 4;
    float bsv = bs[0];
    size_t base = ((size_t)(b * T_DIM + c * CHUNK)) * D_DIM + col0;
    size_t ci = ((size_t)(b * NCHUNK + c)) * D_DIM + col0;
    float ofs[4], ss[4], p[4];
    #pragma unroll
    for (int j = 0; j < 4; j++) { ofs[j] = Of[ci + j]; ss[j] = SSp[ci + j]; p[j] = 0.f; }
    #pragma unroll 8
    for (int t = 0; t < CHUNK; t++) {
        size_t idx = base + (size_t)t * D_DIM;
        ushort4 lv = *(const ushort4*)(la + idx);
        ushort4 xv = *(const ushort4*)(xn + idx);
        u16 lvs[4] = {lv.x, lv.y, lv.z, lv.w};
        u16 xvs[4] = {xv.x, xv.y, xv.z, xv.w};
        u16 os[4];
        #pragma unroll
        for (int j = 0; j < 4; j++) {
            float lav = bf2f(lvs[j]);
            p[j] += lav;
            float scv = __expf(ofs[j] + p[j]);
            float bx = bsv * (1.f - __expf(lav)) * bf2f(xvs[j]);
            ss[j] += bx * scv;
            os[j] = f2bf(ss[j] / (scv + 1e-8f));
        }
        ushort4 o; o.x = os[0]; o.y = os[1]; o.z = os[2]; o.w = os[3];
        *(ushort4*)(osc + idx) = o;
    }
}

// ---------------- GEMM2: out = 0.05*tanh(osc@Wr^T + br) + x ----------------
__global__ __launch_bounds__(512, 2) void gemm2_kernel(const u16* __restrict__ A,
                                                       const u16* __restrict__ Bm,
                                                       const float* __restrict__ bias,
                                                       const float* __restrict__ resid,
                                                       float* __restrict__ out_f) {
    __shared__ __align__(16) u16 ldsA[2][16384];
    __shared__ __align__(16) u16 ldsB[2][16384];
    int flat = blockIdx.y * 4 + blockIdx.x;
    int xcd = flat & 7, p = flat >> 3;
    int tile_m = (xcd * 8 + (p >> 2)) * 256;
    int tile_n = (p & 3) * 256;
    f32x4 acc[8][4] = {};
    gemm256_core(A, Bm, tile_m, tile_n, &ldsA[0][0], &ldsB[0][0], acc);

    int tid = threadIdx.x, wave = tid >> 6, lane = tid & 63;
    int wr = wave >> 2, wc = wave & 3;
    int q = lane >> 4, l = lane & 15;
    #pragma unroll
    for (int mi = 0; mi < 8; mi++) {
        #pragma unroll
        for (int r = 0; r < 4; r++) {
            int row = tile_m + wr * 128 + mi * 16 + q * 4 + r;
            #pragma unroll
            for (int ni = 0; ni < 4; ni++) {
                int col = tile_n + wc * 64 + ni * 16 + l;
                size_t idx = (size_t)row * D_DIM + col;
                float g = fast_tanh(acc[mi][ni][r] + bias[col]);
                out_f[idx] = 0.05f * g + resid[idx];
            }
        }
    }
}

extern "C" void kernel_launch(void* const* d_in, const int* in_sizes, int n_in,
                              void* d_out, int out_size, void* d_ws, size_t ws_size,
                              hipStream_t stream) {
    const float* x   = (const float*)d_in[0];
    const float* lnw = (const float*)d_in[1];
    const float* lnb = (const float*)d_in[2];
    const float* Wf  = (const float*)d_in[3];
    const float* bf_ = (const float*)d_in[4];
    const float* Wr  = (const float*)d_in[5];
    const float* br  = (const float*)d_in[6];
    const float* ab  = (const float*)d_in[7];
    const float* bs  = (const float*)d_in[8];
    float* out = (float*)d_out;

    // workspace (76 MB):
    //   xn  : [ 0,32MB) bf16 layernorm out; later overwritten in-place by scan output
    //   la  : [32,64MB) bf16 log(alpha+1e-8) from GEMM1
    //   Wfc : [64,66MB)  Wrc : [66,68MB)
    //   S,Tb,Of,SSp : 4 x 2MB fp32 at [68,76MB)
    char* w = (char*)d_ws;
    u16* xn  = (u16*)w;
    u16* la  = (u16*)(w + (size_t)33554432);
    u16* Wfc = (u16*)(w + (size_t)67108864);
    u16* Wrc = (u16*)(w + (size_t)69206016);
    float* S   = (float*)(w + (size_t)71303168);
    float* Tb  = S  + 524288;
    float* Of  = Tb + 524288;
    float* SSp = Of + 524288;
    u16* osc = xn;

    ln_conv_kernel<<<dim3(2048 + M_DIM / 4), dim3(256), 0, stream>>>(
        x, lnw, lnb, xn, Wf, Wr, Wfc, Wrc);
    gemm1_kernel<<<dim3(D_DIM / 256, M_DIM / 256), dim3(512), 0, stream>>>(
        xn, Wfc, bf_, ab, bs, la, S, Tb);
    scan_combine<<<dim3(B_DIM * 16), dim3(1024), 0, stream>>>(la, S, Tb, Of, SSp);
    scan_final<<<dim3(B_DIM * NCHUNK), dim3(256), 0, stream>>>(la, xn, bs, Of, SSp, osc);
    gemm2_kernel<<<dim3(D_DIM / 256, M_DIM / 256), dim3(512), 0, stream>>>(
        osc, Wrc, br, x, out);
}

// Round 4
// 273.306 us; speedup vs baseline: 1.4456x; 1.4456x over previous
//
#include <hip/hip_runtime.h>

// B=4, T=4096, D=1024. Inputs/outputs fp32. GEMM in bf16 MFMA.
// Pipeline: ln_conv -> gemm1 (+fused per-chunk scan aggregates) -> combine -> final -> gemm2.
// Numerics: la = log(alpha+1e-8) <= ~1e-8, so global max of cumsum ~= la[t=0] (error <= 4e-5);
// m is read from la row t=0 in combine; no max machinery anywhere.
// R4: R2's 256x256/BK=64 counted-vmcnt core, UNPINNED: barriers are plain s_barrier between
//     compiler memory fences (no sched_barrier(0) -- m141 anti-pattern caused R3's 2x
//     regression). MFMA bursts reordered ks-outer (dep distance 8, bit-identical numerics).
//     T2 16B-slot XOR swizzle (bank conflicts measured 0) + bijective XCD chunking kept.
#define D_DIM 1024
#define B_DIM 4
#define T_DIM 4096
#define M_DIM (B_DIM * T_DIM)   // 16384 rows
#define CHUNK 32
#define NCHUNK (T_DIM / CHUNK)  // 128
#define NWAVE_C 16              // waves per combine block
#define SEG (NCHUNK / NWAVE_C)  // 8 chunks per wave in combine
#define NKT (D_DIM / 64)        // 16 K-tiles of 64

typedef unsigned short u16;
typedef __attribute__((ext_vector_type(8))) __bf16 bf16x8;
typedef __attribute__((ext_vector_type(4))) float f32x4;

__device__ __forceinline__ float bf2f(u16 u) {
    union { unsigned int i; float f; } v;
    v.i = ((unsigned int)u) << 16;
    return v.f;
}
__device__ __forceinline__ u16 f2bf(float f) {
    union { float f; unsigned int i; } v;
    v.f = f;
    unsigned int u = v.i;
    unsigned int r = (u + 0x7fffu + ((u >> 16) & 1u)) >> 16;
    return (u16)r;
}
__device__ __forceinline__ float fast_tanh(float v) {
    float e = __expf(2.f * v);
    return 1.f - 2.f / (e + 1.f);
}

#define GLOAD16(g, l)                                                   \
    __builtin_amdgcn_global_load_lds(                                   \
        (const __attribute__((address_space(1))) void*)(g),             \
        (__attribute__((address_space(3))) void*)(l), 16, 0, 0)

// Plain barrier between compiler memory fences: memory ops cannot cross (correctness),
// but instruction scheduling inside each interval is left to the compiler (no sched_barrier).
#define BAR()                                      \
    do {                                           \
        asm volatile("" ::: "memory");             \
        __builtin_amdgcn_s_barrier();              \
        asm volatile("" ::: "memory");             \
    } while (0)

#define WAITVM(N) asm volatile("s_waitcnt vmcnt(" #N ")" ::: "memory")

// ---------------- fused weight-convert (blocks 0..2047) + wave-per-row LayerNorm ----------
__global__ __launch_bounds__(256) void ln_conv_kernel(const float* __restrict__ x,
                                                      const float* __restrict__ w,
                                                      const float* __restrict__ b,
                                                      u16* __restrict__ xn,
                                                      const float* __restrict__ Wf,
                                                      const float* __restrict__ Wr,
                                                      u16* __restrict__ da,
                                                      u16* __restrict__ db) {
    int tid = threadIdx.x;
    if (blockIdx.x < 2048) {            // convert: 2 x 262144 float4s
        int i = blockIdx.x * 256 + tid;
        const float* s = (i < 262144) ? Wf : Wr;
        u16* dp = (i < 262144) ? da : db;
        int j = i & 262143;
        float4 v = ((const float4*)s)[j];
        ushort4 o;
        o.x = f2bf(v.x); o.y = f2bf(v.y); o.z = f2bf(v.z); o.w = f2bf(v.w);
        ((ushort4*)dp)[j] = o;
        return;
    }
    // LN: one wave per row, 4 rows per block, no __syncthreads
    int wv = tid >> 6, lane = tid & 63;
    int row = (blockIdx.x - 2048) * 4 + wv;
    const float4* xr = (const float4*)(x + (size_t)row * D_DIM);
    float4 xv[4];
    #pragma unroll
    for (int k = 0; k < 4; k++) xv[k] = xr[lane + 64 * k];
    float s = 0.f, s2 = 0.f;
    #pragma unroll
    for (int k = 0; k < 4; k++) {
        s  += xv[k].x + xv[k].y + xv[k].z + xv[k].w;
        s2 += xv[k].x * xv[k].x + xv[k].y * xv[k].y
            + xv[k].z * xv[k].z + xv[k].w * xv[k].w;
    }
    #pragma unroll
    for (int o = 1; o < 64; o <<= 1) {
        s  += __shfl_xor(s, o, 64);
        s2 += __shfl_xor(s2, o, 64);
    }
    float mu = s * (1.0f / D_DIM);
    float var = s2 * (1.0f / D_DIM) - mu * mu;
    float rs = rsqrtf(var + 1e-5f);
    ushort4* xo = (ushort4*)(xn + (size_t)row * D_DIM);
    #pragma unroll
    for (int k = 0; k < 4; k++) {
        float4 wv4 = ((const float4*)w)[lane + 64 * k];
        float4 bv4 = ((const float4*)b)[lane + 64 * k];
        ushort4 o;
        o.x = f2bf((xv[k].x - mu) * rs * wv4.x + bv4.x);
        o.y = f2bf((xv[k].y - mu) * rs * wv4.y + bv4.y);
        o.z = f2bf((xv[k].z - mu) * rs * wv4.z + bv4.z);
        o.w = f2bf((xv[k].w - mu) * rs * wv4.w + bv4.w);
        xo[lane + 64 * k] = o;
    }
}

// ---------------- 256x256 BK=64 counted-vmcnt GEMM core (fills acc[8][4]) ----------------
// A [M][1024], B [N][1024] row-major bf16 (C = A.B^T slice). 512 thr = 8 waves (2m x 4n).
// LDS: [2 dbuf][256 rows][64 cols] per operand, 16B-slot XOR swizzle slot^=(row&7):
// staged via pre-swizzled GLOBAL source (linear gload_lds dest), un-swizzled on ds_read.
// Per K-tile t: {reads + 2 MMQ} BAR {stgA(t+2), MMQ} {stgB(t+2), vmcnt(8)} BAR {MMQ}.
// vmcnt ledger: at tile t's wait, tiles <= t+1 landed, t+2 (8 loads) in flight.
__device__ __forceinline__ void gemm256_core(const u16* __restrict__ AG,
                                             const u16* __restrict__ BG,
                                             int tile_m, int tile_n,
                                             u16* ldsA, u16* ldsB,
                                             f32x4 (*acc)[4]) {
    int tid  = threadIdx.x;
    int wave = tid >> 6, lane = tid & 63;
    int wr = wave >> 2, wc = wave & 3;
    int q = lane >> 4;
    // staging: thread covers LDS bytes j*8192 + tid*16 (j=0..3) => local row j*64+(tid>>3),
    // 16B slot tid&7. Source col-slot pre-swizzled: (tid&7) ^ (row&7).
    int srow = tid >> 3;
    int scol = ((tid & 7) ^ (srow & 7)) * 8;
    const u16* gA = AG + (size_t)(tile_m + srow) * D_DIM + scol;
    const u16* gB = BG + (size_t)(tile_n + srow) * D_DIM + scol;
    int ldst = wave * 512;   // u16 offset: wave-uniform gload dest base within 8KB pass
    // fragment read: local row m, u16 off = m*64 + ((ks*4+q)^(m&7))*8 ; m&7 == lane&7
    int aRow = wr * 128 + (lane & 15);
    int bRow = wc * 64 + (lane & 15);
    int x7 = lane & 7;
    int s0 = (q ^ x7) * 8;          // ks=0 slot
    int s1 = ((4 | q) ^ x7) * 8;    // ks=1 slot

#define STG4(ldsbase, gsrc, koff)                                        \
    do {                                                                 \
        _Pragma("unroll") for (int j = 0; j < 4; j++)                    \
            GLOAD16((gsrc) + (size_t)j * (64 * D_DIM) + (koff),          \
                    (ldsbase) + j * 4096 + ldst);                        \
    } while (0)

// 16 MFMA, ks-outer: adjacent instructions always target different acc (dep distance 8).
// Per-acc order still ks0 then ks1 -> bit-identical accumulation.
#define MMQ(Af, Bf, mo, no)                                              \
    do {                                                                 \
        __builtin_amdgcn_s_setprio(1);                                   \
        _Pragma("unroll") for (int ks_ = 0; ks_ < 2; ks_++)              \
            _Pragma("unroll") for (int mi_ = 0; mi_ < 4; mi_++)          \
                _Pragma("unroll") for (int ni_ = 0; ni_ < 2; ni_++)      \
                    acc[(mo) + mi_][(no) + ni_] =                        \
                        __builtin_amdgcn_mfma_f32_16x16x32_bf16(         \
                            Af[mi_][ks_], Bf[ni_][ks_],                  \
                            acc[(mo) + mi_][(no) + ni_], 0, 0, 0);       \
        __builtin_amdgcn_s_setprio(0);                                   \
    } while (0)

    // prologue: stage t0 (buf0) + t1 (buf1); land t0, keep t1 in flight.
    STG4(ldsA, gA, 0);
    STG4(ldsB, gB, 0);
    STG4(ldsA + 16384, gA, 64);
    STG4(ldsB + 16384, gB, 64);
    WAITVM(8);
    BAR();

    for (int t = 0; t < NKT; t++) {
        int c = t & 1;
        const u16* pA = ldsA + c * 16384 + aRow * 64;
        const u16* pB = ldsB + c * 16384 + bRow * 64;
        bf16x8 A0[4][2], A1[4][2], B0[2][2], B1[2][2];
        #pragma unroll
        for (int mi = 0; mi < 4; mi++) {
            A0[mi][0] = *(const bf16x8*)(pA + mi * 1024 + s0);
            A0[mi][1] = *(const bf16x8*)(pA + mi * 1024 + s1);
        }
        #pragma unroll
        for (int ni = 0; ni < 2; ni++) {
            B0[ni][0] = *(const bf16x8*)(pB + ni * 1024 + s0);
            B0[ni][1] = *(const bf16x8*)(pB + ni * 1024 + s1);
        }
        MMQ(A0, B0, 0, 0);
        #pragma unroll
        for (int mi = 0; mi < 4; mi++) {
            A1[mi][0] = *(const bf16x8*)(pA + (mi + 4) * 1024 + s0);
            A1[mi][1] = *(const bf16x8*)(pA + (mi + 4) * 1024 + s1);
        }
        #pragma unroll
        for (int ni = 0; ni < 2; ni++) {
            B1[ni][0] = *(const bf16x8*)(pB + (ni + 2) * 1024 + s0);
            B1[ni][1] = *(const bf16x8*)(pB + (ni + 2) * 1024 + s1);
        }
        MMQ(A0, B1, 0, 2);
        BAR();   // all reads of buf c complete chip-wide -> safe to overwrite
        if (t + 2 < NKT) STG4(ldsA + c * 16384, gA, (size_t)(t + 2) * 64);
        MMQ(A1, B0, 4, 0);
        if (t + 2 < NKT) {
            STG4(ldsB + c * 16384, gB, (size_t)(t + 2) * 64);
            WAITVM(8);   // lands tile t+1; tile t+2 (8 loads) stays in flight
        } else {
            WAITVM(0);   // tail: land the final tile
        }
        BAR();
        MMQ(A1, B1, 4, 2);
    }
#undef STG4
#undef MMQ
}

// ---------------- GEMM1: alpha=sigmoid(xn@Wf^T+bf+ab); writes la (bf16) and, fused,
// per-chunk scan aggregates S = sum(la over 32 t), Tb = sum(bx*exp(local inclusive cumsum)).
// Wave owns 128x64 = 4 chunks (mi pairs); prefix over q=lane>>4 via shfl_up as before.
__global__ __launch_bounds__(512, 2) void gemm1_kernel(const u16* __restrict__ xn,
                                                       const u16* __restrict__ Wfc,
                                                       const float* __restrict__ bf_,
                                                       const float* __restrict__ ab,
                                                       const float* __restrict__ bs,
                                                       u16* __restrict__ out_la,
                                                       float* __restrict__ Sg,
                                                       float* __restrict__ Tg) {
    __shared__ __align__(16) u16 ldsA[2][16384];
    __shared__ __align__(16) u16 ldsB[2][16384];
    // bijective XCD chunking: 256 blocks = 8 XCD x (8 m-panels x 4 n-tiles)
    int flat = blockIdx.y * 4 + blockIdx.x;
    int xcd = flat & 7, p = flat >> 3;
    int tile_m = (xcd * 8 + (p >> 2)) * 256;
    int tile_n = (p & 3) * 256;
    f32x4 acc[8][4] = {};
    gemm256_core(xn, Wfc, tile_m, tile_n, &ldsA[0][0], &ldsB[0][0], acc);

    // epilogue: C/D layout col=lane&15 (+ni*16), row=(lane>>4)*4+r (+mi*16) [m89-verified]
    int tid = threadIdx.x, wave = tid >> 6, lane = tid & 63;
    int wr = wave >> 2, wc = wave & 3;
    float abv = ab[0], bsv = bs[0];
    int q = lane >> 4, l = lane & 15;
    #pragma unroll
    for (int ni = 0; ni < 4; ni++) {
        int col = tile_n + wc * 64 + ni * 16 + l;
        float bcol = bf_[col];
        #pragma unroll
        for (int ch = 0; ch < 4; ch++) {   // chunk (32 rows) = mi pair {2ch, 2ch+1}
            float lav[2][4], bxv[2][4];
            #pragma unroll
            for (int h = 0; h < 2; h++) {
                int mi = 2 * ch + h;
                #pragma unroll
                for (int r = 0; r < 4; r++) {
                    int row = tile_m + wr * 128 + mi * 16 + q * 4 + r;
                    float z = acc[mi][ni][r] + bcol + abv;
                    float alpha = 1.f / (1.f + __expf(-z));
                    float la_ = __logf(alpha + 1e-8f);
                    float xv = bf2f(xn[(size_t)row * D_DIM + col]);
                    lav[h][r] = la_;
                    bxv[h][r] = bsv * (1.f - alpha) * xv;
                    out_la[(size_t)row * D_DIM + col] = f2bf(la_);
                }
            }
            // wave-local chunk scan: t = h*16 + q*4 + r
            float s0 = lav[0][0] + lav[0][1] + lav[0][2] + lav[0][3];
            float s1 = lav[1][0] + lav[1][1] + lav[1][2] + lav[1][3];
            float x0 = s0, x1 = s1, y;
            y = __shfl_up(x0, 16, 64); if (q >= 1) x0 += y;
            y = __shfl_up(x0, 32, 64); if (q >= 2) x0 += y;
            y = __shfl_up(x1, 16, 64); if (q >= 1) x1 += y;
            y = __shfl_up(x1, 32, 64); if (q >= 2) x1 += y;
            float t0 = __shfl(x0, l + 48, 64);   // totals from q=3 lane
            float t1 = __shfl(x1, l + 48, 64);
            float e0 = x0 - s0, e1 = x1 - s1;    // exclusive prefixes over q
            float pr = e0, Tp = 0.f;
            #pragma unroll
            for (int r = 0; r < 4; r++) { pr += lav[0][r]; Tp += bxv[0][r] * __expf(pr); }
            pr = t0 + e1;
            #pragma unroll
            for (int r = 0; r < 4; r++) { pr += lav[1][r]; Tp += bxv[1][r] * __expf(pr); }
            Tp += __shfl_xor(Tp, 16, 64);
            Tp += __shfl_xor(Tp, 32, 64);
            if (q == 0) {
                int cidx = ((tile_m + wr * 128) >> 5) + ch;   // = b*NCHUNK + chunk
                Sg[(size_t)cidx * D_DIM + col] = t0 + t1;
                Tg[(size_t)cidx * D_DIM + col] = Tp;
            }
        }
    }
}

// ---------------- combine: per (b,d), prefix over 128 chunks. m = la[b, t=0, d]. ----------
__global__ __launch_bounds__(1024) void scan_combine(const u16* __restrict__ la,
                                                     const float* __restrict__ S,
                                                     const float* __restrict__ Tb,
                                                     float* __restrict__ Of,
                                                     float* __restrict__ SSp) {
    __shared__ float lsS[NWAVE_C][64], lsW[NWAVE_C][64];
    int b = blockIdx.x >> 4;
    int dg = blockIdx.x & 15;
    int wave = threadIdx.x >> 6, lane = threadIdx.x & 63;
    int d = dg * 64 + lane;
    float m = bf2f(la[(size_t)(b * T_DIM) * D_DIM + d]);   // cumsum[0] ~= global max
    size_t base = ((size_t)b * NCHUNK) * D_DIM + d;
    int c0 = wave * SEG;

    float OfR[SEG], wR[SEG];
    float Or = 0.f, w = 0.f;
    #pragma unroll
    for (int j = 0; j < SEG; j++) {
        size_t ci = base + (size_t)(c0 + j) * D_DIM;
        OfR[j] = Or;
        wR[j]  = w;
        w  += __expf(Or) * Tb[ci];
        Or += S[ci];
    }
    lsS[wave][lane] = Or; lsW[wave][lane] = w;
    __syncthreads();

    float o = 0.f, s = 0.f, myO = 0.f, myS = 0.f;
    #pragma unroll
    for (int w2 = 0; w2 < NWAVE_C; w2++) {
        if (w2 == wave) { myO = o; myS = s; }
        s += __expf(o - m) * lsW[w2][lane];
        o += lsS[w2][lane];
    }

    float em = __expf(myO - m);
    #pragma unroll
    for (int j = 0; j < SEG; j++) {
        size_t ci = base + (size_t)(c0 + j) * D_DIM;
        Of[ci]  = myO + OfR[j] - m;
        SSp[ci] = myS + em * wR[j];
    }
}

// ---------------- final: scale=exp(Of+p), s_star=SSp+cumsum, out=s_star/(scale+1e-8) -----
// 4 cols/thread; osc aliases xn (reads at idx precede the write at idx, same thread).
__global__ __launch_bounds__(256) void scan_final(const u16* __restrict__ la,
                                                  const u16* __restrict__ xn,
                                                  const float* __restrict__ bs,
                                                  const float* __restrict__ Of,
                                                  const float* __restrict__ SSp,
                                                  u16* __restrict__ osc) {
    int bc = blockIdx.x;
    int b = bc >> 7, c = bc & (NCHUNK - 1);
    int col0 = threadIdx.x * 4;
    float bsv = bs[0];
    size_t base = ((size_t)(b * T_DIM + c * CHUNK)) * D_DIM + col0;
    size_t ci = ((size_t)(b * NCHUNK + c)) * D_DIM + col0;
    float ofs[4], ss[4], p[4];
    #pragma unroll
    for (int j = 0; j < 4; j++) { ofs[j] = Of[ci + j]; ss[j] = SSp[ci + j]; p[j] = 0.f; }
    #pragma unroll 8
    for (int t = 0; t < CHUNK; t++) {
        size_t idx = base + (size_t)t * D_DIM;
        ushort4 lv = *(const ushort4*)(la + idx);
        ushort4 xv = *(const ushort4*)(xn + idx);
        u16 lvs[4] = {lv.x, lv.y, lv.z, lv.w};
        u16 xvs[4] = {xv.x, xv.y, xv.z, xv.w};
        u16 os[4];
        #pragma unroll
        for (int j = 0; j < 4; j++) {
            float lav = bf2f(lvs[j]);
            p[j] += lav;
            float scv = __expf(ofs[j] + p[j]);
            float bx = bsv * (1.f - __expf(lav)) * bf2f(xvs[j]);
            ss[j] += bx * scv;
            os[j] = f2bf(ss[j] / (scv + 1e-8f));
        }
        ushort4 o; o.x = os[0]; o.y = os[1]; o.z = os[2]; o.w = os[3];
        *(ushort4*)(osc + idx) = o;
    }
}

// ---------------- GEMM2: out = 0.05*tanh(osc@Wr^T + br) + x ----------------
__global__ __launch_bounds__(512, 2) void gemm2_kernel(const u16* __restrict__ A,
                                                       const u16* __restrict__ Bm,
                                                       const float* __restrict__ bias,
                                                       const float* __restrict__ resid,
                                                       float* __restrict__ out_f) {
    __shared__ __align__(16) u16 ldsA[2][16384];
    __shared__ __align__(16) u16 ldsB[2][16384];
    int flat = blockIdx.y * 4 + blockIdx.x;
    int xcd = flat & 7, p = flat >> 3;
    int tile_m = (xcd * 8 + (p >> 2)) * 256;
    int tile_n = (p & 3) * 256;
    f32x4 acc[8][4] = {};
    gemm256_core(A, Bm, tile_m, tile_n, &ldsA[0][0], &ldsB[0][0], acc);

    int tid = threadIdx.x, wave = tid >> 6, lane = tid & 63;
    int wr = wave >> 2, wc = wave & 3;
    int q = lane >> 4, l = lane & 15;
    #pragma unroll
    for (int mi = 0; mi < 8; mi++) {
        #pragma unroll
        for (int r = 0; r < 4; r++) {
            int row = tile_m + wr * 128 + mi * 16 + q * 4 + r;
            #pragma unroll
            for (int ni = 0; ni < 4; ni++) {
                int col = tile_n + wc * 64 + ni * 16 + l;
                size_t idx = (size_t)row * D_DIM + col;
                float g = fast_tanh(acc[mi][ni][r] + bias[col]);
                out_f[idx] = 0.05f * g + resid[idx];
            }
        }
    }
}

extern "C" void kernel_launch(void* const* d_in, const int* in_sizes, int n_in,
                              void* d_out, int out_size, void* d_ws, size_t ws_size,
                              hipStream_t stream) {
    const float* x   = (const float*)d_in[0];
    const float* lnw = (const float*)d_in[1];
    const float* lnb = (const float*)d_in[2];
    const float* Wf  = (const float*)d_in[3];
    const float* bf_ = (const float*)d_in[4];
    const float* Wr  = (const float*)d_in[5];
    const float* br  = (const float*)d_in[6];
    const float* ab  = (const float*)d_in[7];
    const float* bs  = (const float*)d_in[8];
    float* out = (float*)d_out;

    // workspace (76 MB):
    //   xn  : [ 0,32MB) bf16 layernorm out; later overwritten in-place by scan output
    //   la  : [32,64MB) bf16 log(alpha+1e-8) from GEMM1
    //   Wfc : [64,66MB)  Wrc : [66,68MB)
    //   S,Tb,Of,SSp : 4 x 2MB fp32 at [68,76MB)
    char* w = (char*)d_ws;
    u16* xn  = (u16*)w;
    u16* la  = (u16*)(w + (size_t)33554432);
    u16* Wfc = (u16*)(w + (size_t)67108864);
    u16* Wrc = (u16*)(w + (size_t)69206016);
    float* S   = (float*)(w + (size_t)71303168);
    float* Tb  = S  + 524288;
    float* Of  = Tb + 524288;
    float* SSp = Of + 524288;
    u16* osc = xn;

    ln_conv_kernel<<<dim3(2048 + M_DIM / 4), dim3(256), 0, stream>>>(
        x, lnw, lnb, xn, Wf, Wr, Wfc, Wrc);
    gemm1_kernel<<<dim3(D_DIM / 256, M_DIM / 256), dim3(512), 0, stream>>>(
        xn, Wfc, bf_, ab, bs, la, S, Tb);
    scan_combine<<<dim3(B_DIM * 16), dim3(1024), 0, stream>>>(la, S, Tb, Of, SSp);
    scan_final<<<dim3(B_DIM * NCHUNK), dim3(256), 0, stream>>>(la, xn, bs, Of, SSp, osc);
    gemm2_kernel<<<dim3(D_DIM / 256, M_DIM / 256), dim3(512), 0, stream>>>(
        osc, Wrc, br, x, out);
}